// Round 7
// baseline (356.611 us; speedup 1.0000x reference)
//
#include <hip/hip_runtime.h>
#include <hip/hip_bf16.h>

#define M_DIM 8192
#define N_DIM 3072
#define K_DIM 3072
#define RANK_ 64

#define BM 256
#define BN 192
#define BK 64
#define NT (K_DIM / BK)   // 48 K-tiles

typedef __attribute__((ext_vector_type(8))) __bf16 bf16x8;
typedef __attribute__((ext_vector_type(4))) float floatx4;
typedef __attribute__((ext_vector_type(8))) unsigned short ushort8;

__device__ __forceinline__ unsigned short f2bf(float f) {
  union { float f; unsigned u; } v;
  v.f = f;
  return (unsigned short)((v.u + 0x7fffu + ((v.u >> 16) & 1u)) >> 16);
}

// ---- Kernel 1: x fp32 -> bf16 (memory-bound, vectorized) ----
__global__ void cvt_x_kernel(const float* __restrict__ x, unsigned short* __restrict__ xb) {
  size_t i = ((size_t)blockIdx.x * 256u + threadIdx.x) * 8u;
  const float4* xp = (const float4*)(x + i);
  float4 a = xp[0];
  float4 b = xp[1];
  ushort8 r;
  r[0] = f2bf(a.x); r[1] = f2bf(a.y); r[2] = f2bf(a.z); r[3] = f2bf(a.w);
  r[4] = f2bf(b.x); r[5] = f2bf(b.y); r[6] = f2bf(b.z); r[7] = f2bf(b.w);
  *(ushort8*)(xb + i) = r;
}

// ---- Kernel 2 v3 (frozen): W_eff = Wq*scale + A@B, bf16 out ----
__global__ __launch_bounds__(256) void build_weff_kernel(
    const int* __restrict__ wq, const float* __restrict__ scale,
    const float* __restrict__ lA, const float* __restrict__ lB,
    unsigned short* __restrict__ weff) {
  __shared__ float sB[64][128];
  __shared__ float sA[128][65];

  const int tid = threadIdx.x;
  const int i0 = blockIdx.x * 128;
  const int o0 = blockIdx.y * 128;

#pragma unroll
  for (int l = 0; l < 8; ++l) {
    int lin = l * 256 + tid;
    int r = lin >> 5;
    int c4 = (lin & 31) * 4;
    *(float4*)&sB[r][c4] = *(const float4*)&lB[(size_t)r * K_DIM + i0 + c4];
  }
#pragma unroll
  for (int l = 0; l < 8; ++l) {
    int lin = l * 256 + tid;
    int o = lin >> 4;
    int c4 = (lin & 15) * 4;
    *(float4*)&sA[o][c4] = *(const float4*)&lA[(size_t)(o0 + o) * RANK_ + c4];
  }
  __syncthreads();

  const int ib = (tid & 15) * 8;
  const int ob = (tid >> 4) * 8;

  float acc[8][8];
#pragma unroll
  for (int oo = 0; oo < 8; ++oo) {
    const int o = o0 + ob + oo;
    const float sc = scale[o];
    const int* wrow = wq + (size_t)o * K_DIM + i0 + ib;
    int4 w0 = *(const int4*)wrow;
    int4 w1 = *(const int4*)(wrow + 4);
    acc[oo][0] = (float)w0.x * sc; acc[oo][1] = (float)w0.y * sc;
    acc[oo][2] = (float)w0.z * sc; acc[oo][3] = (float)w0.w * sc;
    acc[oo][4] = (float)w1.x * sc; acc[oo][5] = (float)w1.y * sc;
    acc[oo][6] = (float)w1.z * sc; acc[oo][7] = (float)w1.w * sc;
  }

  for (int r = 0; r < RANK_; ++r) {
    float4 b0 = *(const float4*)&sB[r][ib];
    float4 b1 = *(const float4*)&sB[r][ib + 4];
#pragma unroll
    for (int oo = 0; oo < 8; ++oo) {
      const float a = sA[ob + oo][r];
      acc[oo][0] += a * b0.x; acc[oo][1] += a * b0.y;
      acc[oo][2] += a * b0.z; acc[oo][3] += a * b0.w;
      acc[oo][4] += a * b1.x; acc[oo][5] += a * b1.y;
      acc[oo][6] += a * b1.z; acc[oo][7] += a * b1.w;
    }
  }

#pragma unroll
  for (int oo = 0; oo < 8; ++oo) {
    ushort8 pk;
#pragma unroll
    for (int ii = 0; ii < 8; ++ii) pk[ii] = f2bf(acc[oo][ii]);
    *(ushort8*)&weff[(size_t)(o0 + ob + oo) * K_DIM + i0 + ib] = pk;
  }
}

// ---- Kernel 3: 256x192 8-wave bf16 GEMM, 2 phases/K-tile (24 MFMA each) ----
// grid 512 = 2 exact passes. A double-buffered (2x32KB), B TRIPLE-buffered
// (3x24KB) -> 136 KiB LDS. B-tribuf is what makes the 2-phase schedule WAR-safe:
//   A(g+1) staged ph1(g): A[(g+1)&1] readers drained at ph2(g-1) lgkm0+barrier.
//   B(g+2) staged ph2(g): B[(g+2)%3] last read at tile g-1 (>=2 barriers ago).
// Gate: end-ph2 vmcnt(3) retires A(g+1) (in-order, m135); B(g+2) flies 2 tiles.
#define MF(A,B,C) __builtin_amdgcn_mfma_f32_16x16x32_bf16(A, B, C, 0, 0, 0)

#define ABASE(b) ((b) * 16384)
#define BBASE(b) (32768 + (b) * 12288)

__global__ __launch_bounds__(512, 2) void gemm8_kernel(
    const unsigned short* __restrict__ xb, const unsigned short* __restrict__ weff,
    const float* __restrict__ bias, float* __restrict__ out) {
  extern __shared__ unsigned short smem[];  // 69632 ushorts = 136 KiB

  const int tid = threadIdx.x;
  const int lane = tid & 63;
  const int wid = tid >> 6;     // 0..7
  const int wm = wid >> 2;      // 0..1  (M)
  const int wn = wid & 3;       // 0..3  (N)

  // XCD-aware bijective swizzle (512 % 8 == 0, cpx = 64)
  const int bid = blockIdx.x;
  const int swz = (bid & 7) * 64 + (bid >> 3);
  const int tileM = swz / (N_DIM / BN);
  const int tileN = swz % (N_DIM / BN);
  const int rowA0 = tileM * BM;
  const int colB0 = tileN * BN;

  const int srow = tid >> 3;
  const int skidx = ((tid & 7) * 8) ^ ((srow & 7) << 3);
  const unsigned short* gAbase = xb + (size_t)(rowA0 + srow) * K_DIM + skidx;
  const unsigned short* gBbase = weff + (size_t)(colB0 + srow) * K_DIM + skidx;
  const int ldsLin = tid * 8;

  auto stageA = [&](int t, int buf) {   // 4 chunks of 64 rows
    const unsigned short* g = gAbase + (size_t)t * BK;
#pragma unroll
    for (int l = 0; l < 4; ++l)
      __builtin_amdgcn_global_load_lds(
          (const __attribute__((address_space(1))) void*)(g + (size_t)l * 64 * K_DIM),
          (__attribute__((address_space(3))) void*)&smem[ABASE(buf) + l * 4096 + ldsLin], 16, 0, 0);
  };
  auto stageB = [&](int t, int buf) {   // 3 chunks of 64 rows
    const unsigned short* g = gBbase + (size_t)t * BK;
#pragma unroll
    for (int l = 0; l < 3; ++l)
      __builtin_amdgcn_global_load_lds(
          (const __attribute__((address_space(1))) void*)(g + (size_t)l * 64 * K_DIM),
          (__attribute__((address_space(3))) void*)&smem[BBASE(buf) + l * 4096 + ldsLin], 16, 0, 0);
  };

  const int lrow = lane & 15;
  const int khalf = lane >> 4;             // 0..3
  const int rsw = (lrow & 7) << 3;
  auto ldA = [&](int b, int mf, int kk) -> bf16x8 {
    return *(const bf16x8*)&smem[ABASE(b) + (wm * 128 + mf * 16 + lrow) * 64 +
                                 ((kk * 32 + khalf * 8) ^ rsw)];
  };
  auto ldB = [&](int b, int nf, int kk) -> bf16x8 {
    return *(const bf16x8*)&smem[BBASE(b) + (wn * 48 + nf * 16 + lrow) * 64 +
                                 ((kk * 32 + khalf * 8) ^ rsw)];
  };

  floatx4 acc[8][3];
#pragma unroll
  for (int m = 0; m < 8; ++m)
#pragma unroll
    for (int n = 0; n < 3; ++n)
      acc[m][n] = (floatx4){0.f, 0.f, 0.f, 0.f};

  // prologue: B(0)->buf0, A(0)->buf0, B(1)->buf1; vmcnt(3): tile0 landed
  stageB(0, 0); stageA(0, 0); stageB(1, 1);
  asm volatile("s_waitcnt vmcnt(3)" ::: "memory");
  __builtin_amdgcn_s_barrier();

  bf16x8 a[8], b[3];
#pragma unroll 6
  for (int g = 0; g < NT; ++g) {
    const int bfA = g & 1;
    const int bfB = g % 3;            // compile-time under unroll 6 (period 6)
    // ---- phase 1 (kk=0): 11 ds_reads, stage A(g+1), 24 MFMA
#pragma unroll
    for (int m = 0; m < 8; ++m) a[m] = ldA(bfA, m, 0);
#pragma unroll
    for (int n = 0; n < 3; ++n) b[n] = ldB(bfB, n, 0);
    if (g + 1 < NT) stageA(g + 1, (g + 1) & 1);
    __builtin_amdgcn_s_barrier();
    asm volatile("s_waitcnt lgkmcnt(0)" ::: "memory");
    __builtin_amdgcn_s_setprio(1);
#pragma unroll
    for (int m = 0; m < 8; ++m)
#pragma unroll
      for (int n = 0; n < 3; ++n) acc[m][n] = MF(a[m], b[n], acc[m][n]);
    __builtin_amdgcn_s_setprio(0);
    __builtin_amdgcn_s_barrier();
    // ---- phase 2 (kk=1): 11 ds_reads, stage B(g+2), 24 MFMA, gate
#pragma unroll
    for (int m = 0; m < 8; ++m) a[m] = ldA(bfA, m, 1);
#pragma unroll
    for (int n = 0; n < 3; ++n) b[n] = ldB(bfB, n, 1);
    if (g + 2 < NT) stageB(g + 2, (g + 2) % 3);
    __builtin_amdgcn_s_barrier();
    asm volatile("s_waitcnt lgkmcnt(0)" ::: "memory");
    __builtin_amdgcn_s_setprio(1);
#pragma unroll
    for (int m = 0; m < 8; ++m)
#pragma unroll
      for (int n = 0; n < 3; ++n) acc[m][n] = MF(a[m], b[n], acc[m][n]);
    __builtin_amdgcn_s_setprio(0);
    if (g < NT - 2) asm volatile("s_waitcnt vmcnt(3)" ::: "memory");
    else            asm volatile("s_waitcnt vmcnt(0)" ::: "memory");
    __builtin_amdgcn_s_barrier();
  }

  // epilogue: C/D layout col=lane&15, row=(lane>>4)*4+j (m89-verified); fuse bias
  const int orow0 = rowA0 + wm * 128;
  const int ocol0 = colB0 + wn * 48;
#pragma unroll
  for (int nf = 0; nf < 3; ++nf) {
    const int col = ocol0 + nf * 16 + lrow;
    const float bvs = bias[col];
#pragma unroll
    for (int mf = 0; mf < 8; ++mf) {
      const int r0 = orow0 + mf * 16 + khalf * 4;
#pragma unroll
      for (int j = 0; j < 4; ++j)
        out[(size_t)(r0 + j) * N_DIM + col] = acc[mf][nf][j] + bvs;
    }
  }
}

extern "C" void kernel_launch(void* const* d_in, const int* in_sizes, int n_in,
                              void* d_out, int out_size, void* d_ws, size_t ws_size,
                              hipStream_t stream) {
  const float* x = (const float*)d_in[0];
  const int* wq = (const int*)d_in[1];
  const float* scale = (const float*)d_in[2];
  const float* lA = (const float*)d_in[3];
  const float* lB = (const float*)d_in[4];
  const float* bias = (const float*)d_in[5];
  float* out = (float*)d_out;

  unsigned short* xb = (unsigned short*)d_ws;           // 8192*3072 bf16 = 50.3 MB
  unsigned short* weff = xb + (size_t)M_DIM * K_DIM;    // 3072*3072 bf16 = 18.9 MB

  hipFuncSetAttribute((const void*)gemm8_kernel,
                      hipFuncAttributeMaxDynamicSharedMemorySize, 139264);

  cvt_x_kernel<<<(M_DIM * (size_t)K_DIM) / (8 * 256), 256, 0, stream>>>(x, xb);
  build_weff_kernel<<<dim3(K_DIM / 128, N_DIM / 128), 256, 0, stream>>>(wq, scale, lA, lB, weff);
  gemm8_kernel<<<(M_DIM / BM) * (N_DIM / BN), 512, 139264, stream>>>(xb, weff, bias, out);
}